// Round 5
// baseline (399.336 us; speedup 1.0000x reference)
//
#include <hip/hip_runtime.h>
#include <stdint.h>

#define B_ 2
#define S_ 1024
#define D_ 4096
#define H_ 32
#define KVH_ 8
#define HD_ 128

typedef short short8 __attribute__((ext_vector_type(8)));
typedef float floatx4 __attribute__((ext_vector_type(4)));

__device__ __forceinline__ ushort f2bf(float f) {
  union { float f; uint32_t u; } v; v.f = f;
  return (ushort)((v.u + 0x7FFFu + ((v.u >> 16) & 1u)) >> 16);
}

__device__ __forceinline__ void gload16(const void* g, void* l) {
  __builtin_amdgcn_global_load_lds((__attribute__((address_space(1))) void*)g,
                                   (__attribute__((address_space(3))) void*)l,
                                   16, 0, 0);
}

// ---------------- f32 -> bf16 convert (8 elems/thread) ----------------
__global__ __launch_bounds__(256) void k_cvt(const float* __restrict__ in,
                                             ushort* __restrict__ out, int n8) {
  int i = blockIdx.x * 256 + threadIdx.x;
  if (i >= n8) return;
  const float4* p = (const float4*)in + (size_t)i * 2;
  float4 a = p[0], b = p[1];
  ushort o8[8] = {f2bf(a.x), f2bf(a.y), f2bf(a.z), f2bf(a.w),
                  f2bf(b.x), f2bf(b.y), f2bf(b.z), f2bf(b.w)};
  *(uint4*)(out + (size_t)i * 8) = *(uint4*)o8;
}

// ---- f32 [R x C] -> bf16 transposed [C x R]; 64x64 tiles, vectorized ----
__global__ __launch_bounds__(256) void k_tr4(const float* __restrict__ in,
                                             ushort* __restrict__ out,
                                             int in_stride, int out_stride) {
  __shared__ float t[64][65];
  const int n0 = blockIdx.x * 64, k0 = blockIdx.y * 64;
  const int c4 = (threadIdx.x & 15) * 4, r = threadIdx.x >> 4;  // r 0..15
#pragma unroll
  for (int rr = 0; rr < 64; rr += 16) {
    float4 v = *(const float4*)&in[(size_t)(k0 + r + rr) * in_stride + n0 + c4];
    t[r + rr][c4] = v.x; t[r + rr][c4 + 1] = v.y;
    t[r + rr][c4 + 2] = v.z; t[r + rr][c4 + 3] = v.w;
  }
  __syncthreads();
#pragma unroll
  for (int rr = 0; rr < 64; rr += 16) {
    const int n = r + rr;
    ushort o4[4] = {f2bf(t[c4][n]), f2bf(t[c4 + 1][n]),
                    f2bf(t[c4 + 2][n]), f2bf(t[c4 + 3][n])};
    *(uint2*)&out[(size_t)(n0 + n) * out_stride + k0 + c4] = *(uint2*)o4;
  }
}

// ------------- xa[m][0..3] = x[m,:] @ [lora_q_a | lora_v_a] -------------
__global__ __launch_bounds__(256) void k_lora(const float* __restrict__ x,
                                              const float* __restrict__ qa,
                                              const float* __restrict__ va,
                                              float* __restrict__ xa) {
  int row = blockIdx.x * 4 + (threadIdx.x >> 6);
  int lane = threadIdx.x & 63;
  const float* xr = x + (size_t)row * D_;
  float a0 = 0, a1 = 0, a2 = 0, a3 = 0;
  for (int k = lane; k < D_; k += 64) {
    float xv = xr[k];
    a0 += xv * qa[2 * k];  a1 += xv * qa[2 * k + 1];
    a2 += xv * va[2 * k];  a3 += xv * va[2 * k + 1];
  }
#pragma unroll
  for (int off = 32; off; off >>= 1) {
    a0 += __shfl_down(a0, off, 64);
    a1 += __shfl_down(a1, off, 64);
    a2 += __shfl_down(a2, off, 64);
    a3 += __shfl_down(a3, off, 64);
  }
  if (lane == 0) {
    float* o = xa + (size_t)row * 4;
    o[0] = a0; o[1] = a1; o[2] = a2; o[3] = a3;
  }
}

// ------------- out[i] = base[i] + p1[i] + p2[i] + p3[i] (in-place base) ----
__global__ __launch_bounds__(256) void k_add3(float* __restrict__ o,
                                              const float* __restrict__ p1,
                                              const float* __restrict__ p2,
                                              const float* __restrict__ p3, int n4) {
  int i = blockIdx.x * 256 + threadIdx.x;
  if (i >= n4) return;
  float4 a = ((const float4*)o)[i];
  float4 b = ((const float4*)p1)[i];
  float4 c = ((const float4*)p2)[i];
  float4 d = ((const float4*)p3)[i];
  float4 r = {a.x + b.x + c.x + d.x, a.y + b.y + c.y + d.y,
              a.z + b.z + c.z + d.z, a.w + b.w + c.w + d.w};
  ((float4*)o)[i] = r;
}

// ==================== 256x256 8-phase/2-tile bf16 GEMM ====================
// C[M x N] = A[M x K] * Bt[N x K]^T (+ rank-2 LoRA epilogue).
// 8 waves (2Mx4N), BK=64, 128KB LDS dbuf, 1 half-tile staged per phase,
// vmcnt(6) at P4/P8 only, lgkmcnt(8) pre-barrier in 12-read phases.
// gridDim.z = split-K ways (1 or 4); z selects output pointer.
#define STAGE_A(HALF, KT) do {                                               \
    const ushort* gp_ = A + (size_t)(m0 + (HALF) * 128 + w * 16 + srow) * Kz \
                          + kz0 + (KT) * 64 + scol;                          \
    char* lp_ = lds + ((KT) & 1) * 65536 + (HALF) * 16384 + w * 2048;        \
    gload16(gp_, lp_);                                                       \
    gload16(gp_ + 8 * Kz, lp_ + 1024);                                       \
  } while (0)

#define STAGE_B(HALF, KT) do {                                               \
    const ushort* gp_ = Bt + (size_t)(n0 + (HALF) * 128 + w * 16 + srow) * Kz\
                          + kz0 + (KT) * 64 + scol;                          \
    char* lp_ = lds + ((KT) & 1) * 65536 + 32768 + (HALF) * 16384 + w * 2048;\
    gload16(gp_, lp_);                                                       \
    gload16(gp_ + 8 * Kz, lp_ + 1024);                                       \
  } while (0)

#define LOAD_AF(QA, BUF) do {                                                \
    const char* ab_ = lds + (BUF) * 65536 + (QA) * 16384 + (wr * 64 + lr) * 128; \
    _Pragma("unroll") for (int fr = 0; fr < 4; fr++)                         \
    _Pragma("unroll") for (int ks = 0; ks < 2; ks++)                         \
      af[fr][ks] = *(const short8*)(ab_ + fr * 2048 + (((ks * 4 + g) * 16) ^ swz)); \
  } while (0)

#define LOAD_BF(QB, BUF, BF) do {                                            \
    const char* bb_ = lds + (BUF) * 65536 + 32768 + (QB) * 16384 + (wc * 32 + lr) * 128; \
    _Pragma("unroll") for (int fc = 0; fc < 2; fc++)                         \
    _Pragma("unroll") for (int ks = 0; ks < 2; ks++)                         \
      BF[fc][ks] = *(const short8*)(bb_ + fc * 2048 + (((ks * 4 + g) * 16) ^ swz)); \
  } while (0)

#define MFMA16(QA, QB, BF) do {                                              \
    __builtin_amdgcn_s_setprio(1);                                           \
    _Pragma("unroll") for (int fr = 0; fr < 4; fr++)                         \
    _Pragma("unroll") for (int fc = 0; fc < 2; fc++)                         \
    _Pragma("unroll") for (int ks = 0; ks < 2; ks++)                         \
      acc[(QA) * 4 + fr][(QB) * 2 + fc] = __builtin_amdgcn_mfma_f32_16x16x32_bf16( \
          af[fr][ks], BF[fc][ks], acc[(QA) * 4 + fr][(QB) * 2 + fc], 0, 0, 0);     \
    __builtin_amdgcn_s_setprio(0);                                           \
  } while (0)

#define GBAR __builtin_amdgcn_s_barrier()
#define LGKM0 asm volatile("s_waitcnt lgkmcnt(0)" ::: "memory")
#define LGKM8 asm volatile("s_waitcnt lgkmcnt(8)" ::: "memory")
#define VMCNT6 asm volatile("s_waitcnt vmcnt(6)" ::: "memory")
#define VMCNT0 asm volatile("s_waitcnt vmcnt(0)" ::: "memory")

__global__ __launch_bounds__(512, 2) void k_gemm8(const ushort* __restrict__ A,
                                                  const ushort* __restrict__ Bt,
                                                  float* __restrict__ C0,
                                                  float* __restrict__ C1,
                                                  float* __restrict__ C2,
                                                  float* __restrict__ C3,
                                                  int N, int K,
                                                  const float* __restrict__ xa,
                                                  const float* __restrict__ qb,
                                                  const float* __restrict__ vb) {
  __shared__ char lds[131072];
  // bijective XCD swizzle within a z-slice (nwg % 8 == 0 for all launches)
  const int nbx = gridDim.x;
  const int nwg = nbx * gridDim.y;
  const int flat = blockIdx.y * nbx + blockIdx.x;
  const int swz_id = (flat & 7) * (nwg >> 3) + (flat >> 3);
  const int m0 = (swz_id / nbx) * 256, n0 = (swz_id % nbx) * 256;
  // split-K
  const int kspan = K / gridDim.z;
  const int kz0 = blockIdx.z * kspan;
  const int NK = kspan >> 6;
  const int NJ = NK >> 1;  // 2 K-tiles per iteration
  float* __restrict__ Cout = (blockIdx.z < 2) ? (blockIdx.z ? C1 : C0)
                                              : (blockIdx.z == 2 ? C2 : C3);

  const int tid = threadIdx.x, lane = tid & 63, w = tid >> 6;
  const int wr = w >> 2, wc = w & 3;  // 2 x 4 waves
  const int lr = lane & 15, g = lane >> 4;
  const int swz = (lr & 7) * 16;
  const size_t Kz = (size_t)K;
  const int srow = lane >> 3;                           // 0..7
  const int scol = ((lane & 7) ^ (srow & 7)) * 8;       // pre-swizzled source col

  floatx4 acc[8][4] = {};
  short8 af[4][2], bf0[2][2], bf1[2][2];

  // prologue: 7 half-tiles staged (tile0 complete + A0,B0,A1 of tile1)
  STAGE_A(0, 0); STAGE_B(0, 0); STAGE_A(1, 0); STAGE_B(1, 0);
  STAGE_A(0, 1); STAGE_B(0, 1); STAGE_A(1, 1);
  VMCNT6;  // tile 0 landed; 3 halves of tile 1 in flight
  GBAR;

  for (int j = 0; j < NJ; ++j) {
    const int t0 = 2 * j, t1 = 2 * j + 1;
    const bool last = (j == NJ - 1);
    // P1: Q(A0,B0) of t0 [buf0]; stage B1(t1); 12 reads -> lgkmcnt(8)
    LOAD_AF(0, 0);
    LOAD_BF(0, 0, bf0);
    STAGE_B(1, t1);
    LGKM8;
    GBAR; LGKM0; MFMA16(0, 0, bf0); GBAR;
    // P2: Q(A0,B1) t0; stage A0(t0+2)
    LOAD_BF(1, 0, bf1);
    if (t0 + 2 < NK) STAGE_A(0, t0 + 2);
    GBAR; LGKM0; MFMA16(0, 1, bf1); GBAR;
    // P3: Q(A1,B1) t0; stage B0(t0+2)
    LOAD_AF(1, 0);
    if (t0 + 2 < NK) STAGE_B(0, t0 + 2);
    GBAR; LGKM0; MFMA16(1, 1, bf1); GBAR;
    // P4: Q(A1,B0) t0; stage A1(t0+2); wait -> tile t1 complete
    if (t0 + 2 < NK) STAGE_A(1, t0 + 2);
    if (last) { VMCNT0; } else { VMCNT6; }
    GBAR; LGKM0; MFMA16(1, 0, bf0); GBAR;
    // P5: Q(A0,B0) of t1 [buf1]; stage B1(t0+2); 12 reads -> lgkmcnt(8)
    LOAD_AF(0, 1);
    LOAD_BF(0, 1, bf0);
    if (t0 + 2 < NK) STAGE_B(1, t0 + 2);
    LGKM8;
    GBAR; LGKM0; MFMA16(0, 0, bf0); GBAR;
    // P6: Q(A0,B1) t1; stage A0(t1+2)
    LOAD_BF(1, 1, bf1);
    if (t1 + 2 < NK) STAGE_A(0, t1 + 2);
    GBAR; LGKM0; MFMA16(0, 1, bf1); GBAR;
    // P7: Q(A1,B1) t1; stage B0(t1+2)
    LOAD_AF(1, 1);
    if (t1 + 2 < NK) STAGE_B(0, t1 + 2);
    GBAR; LGKM0; MFMA16(1, 1, bf1); GBAR;
    // P8: Q(A1,B0) t1; stage A1(t1+2); wait -> tile t0+2 complete
    if (t1 + 2 < NK) STAGE_A(1, t1 + 2);
    if (last) { VMCNT0; } else { VMCNT6; }
    GBAR; LGKM0; MFMA16(1, 0, bf0); GBAR;
  }

  // epilogue: C write + optional rank-2 LoRA (float4-hoisted row factors)
#pragma unroll
  for (int qa = 0; qa < 2; qa++)
#pragma unroll
    for (int fr = 0; fr < 4; fr++) {
      const int mb = m0 + qa * 128 + wr * 64 + fr * 16 + g * 4;
      float4 xa4[4];
      if (xa) {
#pragma unroll
        for (int r = 0; r < 4; r++)
          xa4[r] = *(const float4*)&xa[(size_t)(mb + r) * 4];
      }
#pragma unroll
      for (int qb_ = 0; qb_ < 2; qb_++)
#pragma unroll
        for (int fc = 0; fc < 2; fc++) {
          const int n = n0 + qb_ * 128 + wc * 32 + fc * 16 + lr;
          float b0 = 0.f, b1 = 0.f;
          bool lq = false, lv = false;
          if (xa) {
            if (n < 4096) { lq = true; b0 = qb[n]; b1 = qb[4096 + n]; }
            else if (n >= 5120) { lv = true; b0 = vb[n - 5120]; b1 = vb[1024 + n - 5120]; }
          }
#pragma unroll
          for (int r = 0; r < 4; r++) {
            float c = acc[qa * 4 + fr][qb_ * 2 + fc][r];
            if (lq)      c += xa4[r].x * b0 + xa4[r].y * b1;
            else if (lv) c += xa4[r].z * b0 + xa4[r].w * b1;
            Cout[(size_t)(mb + r) * N + n] = c;
          }
        }
    }
}

// ---- RoPE (interleaved pairs) + repack to (b,h,s,d) bf16 for Q and K ----
__global__ __launch_bounds__(256) void k_rope(const float* __restrict__ xqkv,
                                              const float* __restrict__ fcos,
                                              const float* __restrict__ fsin,
                                              ushort* __restrict__ Qb,
                                              ushort* __restrict__ Kb) {
  const int s = blockIdx.x, b = blockIdx.y;
  const float* row = xqkv + (size_t)(b * S_ + s) * 6144;
#pragma unroll
  for (int it = 0; it < 8; it++) {  // Q: 32 heads * 64 pairs
    int p2 = it * 256 + threadIdx.x;
    int h = p2 >> 6, p = p2 & 63;
    float2 ab = *(const float2*)(row + h * 128 + 2 * p);
    float c = fcos[s * 64 + p], sn = fsin[s * 64 + p];
    uint32_t pk = (uint32_t)f2bf(ab.x * c - ab.y * sn) |
                  ((uint32_t)f2bf(ab.x * sn + ab.y * c) << 16);
    *(uint32_t*)(Qb + ((size_t)(b * H_ + h) * S_ + s) * HD_ + 2 * p) = pk;
  }
#pragma unroll
  for (int it = 0; it < 2; it++) {  // K: 8 heads * 64 pairs
    int p2 = it * 256 + threadIdx.x;
    int h = p2 >> 6, p = p2 & 63;
    float2 ab = *(const float2*)(row + 4096 + h * 128 + 2 * p);
    float c = fcos[s * 64 + p], sn = fsin[s * 64 + p];
    uint32_t pk = (uint32_t)f2bf(ab.x * c - ab.y * sn) |
                  ((uint32_t)f2bf(ab.x * sn + ab.y * c) << 16);
    *(uint32_t*)(Kb + ((size_t)(b * KVH_ + h) * S_ + s) * HD_ + 2 * p) = pk;
  }
}

// ==================== flash attention, LDS-staged K/V ====================
#define FSTAGE(T, DB) do {                                                   \
    _Pragma("unroll") for (int i_ = 0; i_ < 4; i_++) {                       \
      gload16(Kg + (size_t)((T) * 64 + i_ * 16 + k_srow) * HD_ + k_scol,     \
              fls + (DB) * 16384 + i_ * 4096 + w * 1024);                    \
      gload16(Vg + (size_t)(i_ * 32 + v_srow) * S_ + (T) * 64 + v_scol,      \
              fls + 32768 + (DB) * 16384 + i_ * 4096 + w * 1024);            \
    }                                                                        \
  } while (0)

__global__ __launch_bounds__(256, 2) void k_flash(const ushort* __restrict__ Qb,
                                                  const ushort* __restrict__ Kb,
                                                  const ushort* __restrict__ Vt,
                                                  ushort* __restrict__ attn) {
  __shared__ char fls[73728];  // K dbuf 32KB | V dbuf 32KB | P 8KB
  const int qblk = (gridDim.x - 1) - blockIdx.x;  // heavy blocks first
  const int h = blockIdx.y, b = blockIdx.z;
  const int kvh = h >> 2;
  const int tid = threadIdx.x, w = tid >> 6, lane = tid & 63;
  const int lr = lane & 15, g = lane >> 4;
  const int swz = (lr & 7) * 16;
  const int qr0 = qblk * 64 + w * 16;
  const ushort* Qrow = Qb + ((size_t)(b * H_ + h) * S_ + qr0 + lr) * HD_;
  short8 qf[4];
#pragma unroll
  for (int ks = 0; ks < 4; ks++) qf[ks] = *(const short8*)(Qrow + ks * 32 + g * 8);
  const ushort* Kg = Kb + (size_t)(b * KVH_ + kvh) * S_ * HD_;
  const ushort* Vg = Vt + (size_t)(b * KVH_ + kvh) * HD_ * S_;
  char* Pw = fls + 65536 + w * 2048;
  const int q7 = lr & 7;
  const int k_srow = tid >> 4;                          // 0..15
  const int k_scol = ((tid & 15) ^ (k_srow & 7)) * 8;   // pre-swizzled
  const int v_srow = tid >> 3;                          // 0..31
  const int v_scol = ((tid & 7) ^ (v_srow & 7)) * 8;

  float m_run = -1e30f, l_run = 0.f;
  floatx4 o[8] = {};
  const int nt = qblk + 1;

  FSTAGE(0, 0);
  asm volatile("s_waitcnt vmcnt(0)" ::: "memory");
  __builtin_amdgcn_s_barrier();

  for (int t = 0; t < nt; t++) {
    const int cur = t & 1;
    if (t + 1 < nt) FSTAGE(t + 1, cur ^ 1);
    const char* Kl = fls + cur * 16384;
    const char* Vl = fls + 32768 + cur * 16384;
    floatx4 s4[4] = {};
    __builtin_amdgcn_s_setprio(1);
#pragma unroll
    for (int mf = 0; mf < 4; mf++) {
      const char* Krow = Kl + (mf * 16 + lr) * 256;
#pragma unroll
      for (int ks = 0; ks < 4; ks++) {
        short8 kf = *(const short8*)(Krow + (((ks * 4 + g) * 16) ^ swz));
        s4[mf] = __builtin_amdgcn_mfma_f32_16x16x32_bf16(kf, qf[ks], s4[mf], 0, 0, 0);
      }
    }
    __builtin_amdgcn_s_setprio(0);
    const float scale = 0.088388347648318447f;  // 1/sqrt(128)
    float tm = -1e30f;
    if (t == nt - 1) {
#pragma unroll
      for (int mf = 0; mf < 4; mf++)
#pragma unroll
        for (int r = 0; r < 4; r++) {
          int kv = t * 64 + mf * 16 + g * 4 + r;
          float v = (kv > qr0 + lr) ? -1e30f : s4[mf][r] * scale;
          s4[mf][r] = v;
          tm = fmaxf(tm, v);
        }
    } else {
#pragma unroll
      for (int mf = 0; mf < 4; mf++)
#pragma unroll
        for (int r = 0; r < 4; r++) {
          float v = s4[mf][r] * scale;
          s4[mf][r] = v;
          tm = fmaxf(tm, v);
        }
    }
    tm = fmaxf(tm, __shfl_xor(tm, 16, 64));
    tm = fmaxf(tm, __shfl_xor(tm, 32, 64));
    float m_new = fmaxf(m_run, tm);
    float corr = __expf(m_run - m_new);
    float rs = 0.f;
#pragma unroll
    for (int mf = 0; mf < 4; mf++)
#pragma unroll
      for (int r = 0; r < 4; r++) {
        float p = __expf(s4[mf][r] - m_new);
        s4[mf][r] = p;
        rs += p;
      }
    rs += __shfl_xor(rs, 16, 64);
    rs += __shfl_xor(rs, 32, 64);
    l_run = l_run * corr + rs;
    m_run = m_new;
#pragma unroll
    for (int r = 0; r < 4; r++) {
      float cr = __shfl(corr, g * 4 + r, 64);
#pragma unroll
      for (int nf = 0; nf < 8; nf++) o[nf][r] *= cr;
    }
    // P^T -> LDS (per-wave buffer, XOR-swizzled)
#pragma unroll
    for (int mf = 0; mf < 4; mf++) {
      uint2 pv;
      pv.x = (uint32_t)f2bf(s4[mf][0]) | ((uint32_t)f2bf(s4[mf][1]) << 16);
      pv.y = (uint32_t)f2bf(s4[mf][2]) | ((uint32_t)f2bf(s4[mf][3]) << 16);
      *(uint2*)(Pw + lr * 128 + ((mf * 32 + g * 8) ^ (q7 << 4))) = pv;
    }
    // PV: O += P * V (V fragments from LDS, conflict-free)
    __builtin_amdgcn_s_setprio(1);
#pragma unroll
    for (int ks2 = 0; ks2 < 2; ks2++) {
      short8 pa = *(const short8*)(Pw + lr * 128 + ((ks2 * 64 + g * 16) ^ (q7 << 4)));
#pragma unroll
      for (int nf = 0; nf < 8; nf++) {
        short8 vf = *(const short8*)(Vl + (nf * 16 + lr) * 128 + (((ks2 * 4 + g) * 16) ^ swz));
        o[nf] = __builtin_amdgcn_mfma_f32_16x16x32_bf16(pa, vf, o[nf], 0, 0, 0);
      }
    }
    __builtin_amdgcn_s_setprio(0);
    asm volatile("s_waitcnt vmcnt(0)" ::: "memory");
    __builtin_amdgcn_s_barrier();
  }
  float linv = 1.0f / l_run;
  ushort* outp = attn + ((size_t)(b * S_) + qr0) * 4096 + h * 128;
#pragma unroll
  for (int r = 0; r < 4; r++) {
    float li = __shfl(linv, g * 4 + r, 64);
    ushort* orow = outp + (size_t)(g * 4 + r) * 4096;
#pragma unroll
    for (int nf = 0; nf < 8; nf++)
      orow[nf * 16 + lr] = f2bf(o[nf][r] * li);
  }
}

extern "C" void kernel_launch(void* const* d_in, const int* in_sizes, int n_in,
                              void* d_out, int out_size, void* d_ws, size_t ws_size,
                              hipStream_t stream) {
  (void)in_sizes; (void)n_in; (void)out_size; (void)ws_size;
  const float* x    = (const float*)d_in[0];
  const float* wq   = (const float*)d_in[1];
  const float* wk   = (const float*)d_in[2];
  const float* wv   = (const float*)d_in[3];
  const float* wo   = (const float*)d_in[4];
  const float* lqa  = (const float*)d_in[5];
  const float* lqb  = (const float*)d_in[6];
  const float* lva  = (const float*)d_in[7];
  const float* lvb  = (const float*)d_in[8];
  const float* fcos = (const float*)d_in[9];
  const float* fsin = (const float*)d_in[10];

  char* ws = (char*)d_ws;
  ushort* xb   = (ushort*)(ws + 0);           // x bf16              [0,16) MB
  ushort* wT   = (ushort*)(ws + 16777216);    // [wq|wk|wv]^T bf16   [16,64) MB (dead after QKV gemm)
  ushort* woT  = (ushort*)(ws + 67108864);    // wo^T bf16           [64,96) MB
  float*  xqkv = (float*) (ws + 100663296);   // 2048x6144 f32       [96,144) MB (dead after rope/V-tr)
  ushort* Qb   = (ushort*)(ws + 150994944);   // (b,h,s,d) bf16      [144,160) MB
  ushort* Kb   = (ushort*)(ws + 167772160);   // (b,kvh,s,d) bf16    [160,164) MB
  ushort* Vt   = (ushort*)(ws + 171966464);   // (b,kvh,d,s) bf16    [164,168) MB
  ushort* attn = (ushort*)(ws + 176160768);   // 2048x4096 bf16      [168,184) MB
  float*  xa   = (float*) (ws + 192937984);   // 2048x4 f32          [184,...)
  // split-K partials (32 MB each) in regions dead by out-proj time:
  float*  p1   = (float*) (ws + 0);           // [0,32)  = xb+wT head
  float*  p2   = (float*) (ws + 33554432);    // [32,64) = wT tail
  float*  p3   = (float*) (ws + 100663296);   // [96,128) = xqkv head

  // 1) conversions / transposes (vectorized)
  k_cvt<<<4096, 256, 0, stream>>>(x, xb, 1048576);
  k_tr4<<<dim3(64, 64), 256, 0, stream>>>(wq, wT, 4096, 4096);
  k_tr4<<<dim3(16, 64), 256, 0, stream>>>(wk, wT + (size_t)4096 * 4096, 1024, 4096);
  k_tr4<<<dim3(16, 64), 256, 0, stream>>>(wv, wT + (size_t)5120 * 4096, 1024, 4096);
  k_tr4<<<dim3(64, 64), 256, 0, stream>>>(wo, woT, 4096, 4096);
  // 2) LoRA rank-2 projections
  k_lora<<<512, 256, 0, stream>>>(x, lqa, lva, xa);
  // 3) fused QKV GEMM + LoRA epilogue -> xqkv f32 (grid 24x8 = 192 wg)
  k_gemm8<<<dim3(24, 8, 1), 512, 0, stream>>>(xb, wT, xqkv, nullptr, nullptr,
                                              nullptr, 6144, 4096, xa, lqb, lvb);
  // 4) RoPE + repack Q,K ; V transpose (per batch)
  k_rope<<<dim3(1024, 2), 256, 0, stream>>>(xqkv, fcos, fsin, Qb, Kb);
  k_tr4<<<dim3(16, 16), 256, 0, stream>>>(xqkv + 5120, Vt, 6144, 1024);
  k_tr4<<<dim3(16, 16), 256, 0, stream>>>(xqkv + (size_t)1024 * 6144 + 5120, Vt + 1048576, 6144, 1024);
  // 5) flash attention -> attn bf16 (2048 x 4096)
  k_flash<<<dim3(16, 32, 2), 256, 0, stream>>>(Qb, Kb, Vt, attn);
  // 6) output projection, split-K x4 (512 wg = 2 blocks/CU) -> d_out + 3 partials
  k_gemm8<<<dim3(16, 8, 4), 512, 0, stream>>>(attn, woT, (float*)d_out, p1, p2, p3,
                                              4096, 4096, nullptr, nullptr, nullptr);
  k_add3<<<8192, 256, 0, stream>>>((float*)d_out, p1, p2, p3, 2097152);
}

// Round 6
// 335.075 us; speedup vs baseline: 1.1918x; 1.1918x over previous
//
#include <hip/hip_runtime.h>
#include <stdint.h>

#define B_ 2
#define S_ 1024
#define D_ 4096
#define H_ 32
#define KVH_ 8
#define HD_ 128

typedef short short8 __attribute__((ext_vector_type(8)));
typedef float floatx4 __attribute__((ext_vector_type(4)));

__device__ __forceinline__ ushort f2bf(float f) {
  union { float f; uint32_t u; } v; v.f = f;
  return (ushort)((v.u + 0x7FFFu + ((v.u >> 16) & 1u)) >> 16);
}

__device__ __forceinline__ void gload16(const void* g, void* l) {
  __builtin_amdgcn_global_load_lds((__attribute__((address_space(1))) void*)g,
                                   (__attribute__((address_space(3))) void*)l,
                                   16, 0, 0);
}

// ---- fused: x f32 -> bf16  AND  xa = x @ [lora_q_a | lora_v_a] ----
__global__ __launch_bounds__(256) void k_cvtlora(const float* __restrict__ x,
                                                 const float* __restrict__ qa,
                                                 const float* __restrict__ va,
                                                 ushort* __restrict__ xb,
                                                 float* __restrict__ xa) {
  const int row = blockIdx.x, t = threadIdx.x;
  const float* xr = x + (size_t)row * D_;
  ushort* xo = xb + (size_t)row * D_;
  float a0 = 0, a1 = 0, a2 = 0, a3 = 0;
#pragma unroll
  for (int it = 0; it < 4; it++) {
    const int i = it * 1024 + t * 4;
    float4 v = *(const float4*)(xr + i);
    ushort o4[4] = {f2bf(v.x), f2bf(v.y), f2bf(v.z), f2bf(v.w)};
    *(uint2*)(xo + i) = *(uint2*)o4;
    float4 q0 = *(const float4*)(qa + 2 * i);
    float4 q1 = *(const float4*)(qa + 2 * i + 4);
    float4 w0 = *(const float4*)(va + 2 * i);
    float4 w1 = *(const float4*)(va + 2 * i + 4);
    a0 += v.x * q0.x + v.y * q0.z + v.z * q1.x + v.w * q1.z;
    a1 += v.x * q0.y + v.y * q0.w + v.z * q1.y + v.w * q1.w;
    a2 += v.x * w0.x + v.y * w0.z + v.z * w1.x + v.w * w1.z;
    a3 += v.x * w0.y + v.y * w0.w + v.z * w1.y + v.w * w1.w;
  }
#pragma unroll
  for (int off = 32; off; off >>= 1) {
    a0 += __shfl_down(a0, off, 64);
    a1 += __shfl_down(a1, off, 64);
    a2 += __shfl_down(a2, off, 64);
    a3 += __shfl_down(a3, off, 64);
  }
  __shared__ float red[4][4];
  const int w = t >> 6, lane = t & 63;
  if (lane == 0) { red[w][0] = a0; red[w][1] = a1; red[w][2] = a2; red[w][3] = a3; }
  __syncthreads();
  if (t < 4)
    xa[(size_t)row * 4 + t] = red[0][t] + red[1][t] + red[2][t] + red[3][t];
}

// ---- f32 [R x C] -> bf16 transposed [C x R]; 64x64 tiles, vectorized ----
__global__ __launch_bounds__(256) void k_tr4(const float* __restrict__ in,
                                             ushort* __restrict__ out,
                                             int in_stride, int out_stride) {
  __shared__ float t[64][65];
  const int n0 = blockIdx.x * 64, k0 = blockIdx.y * 64;
  const int c4 = (threadIdx.x & 15) * 4, r = threadIdx.x >> 4;  // r 0..15
#pragma unroll
  for (int rr = 0; rr < 64; rr += 16) {
    float4 v = *(const float4*)&in[(size_t)(k0 + r + rr) * in_stride + n0 + c4];
    t[r + rr][c4] = v.x; t[r + rr][c4 + 1] = v.y;
    t[r + rr][c4 + 2] = v.z; t[r + rr][c4 + 3] = v.w;
  }
  __syncthreads();
#pragma unroll
  for (int rr = 0; rr < 64; rr += 16) {
    const int n = r + rr;
    ushort o4[4] = {f2bf(t[c4][n]), f2bf(t[c4 + 1][n]),
                    f2bf(t[c4 + 2][n]), f2bf(t[c4 + 3][n])};
    *(uint2*)&out[(size_t)(n0 + n) * out_stride + k0 + c4] = *(uint2*)o4;
  }
}

// ---------------- partial add (split-K reduction) ----------------
__global__ __launch_bounds__(256) void k_add(const float* __restrict__ a,
                                             const float* __restrict__ b,
                                             float* __restrict__ o, int n4) {
  int i = blockIdx.x * 256 + threadIdx.x;
  if (i >= n4) return;
  float4 x = ((const float4*)a)[i], y = ((const float4*)b)[i];
  float4 r = {x.x + y.x, x.y + y.y, x.z + y.z, x.w + y.w};
  ((float4*)o)[i] = r;
}

#define GBAR __builtin_amdgcn_s_barrier()
#define LGKM0 asm volatile("s_waitcnt lgkmcnt(0)" ::: "memory")
#define LGKM8 asm volatile("s_waitcnt lgkmcnt(8)" ::: "memory")
#define VMCNT0 asm volatile("s_waitcnt vmcnt(0)" ::: "memory")

// ==================== QKV GEMM: 128x384 tile, 256 blocks ====================
// C[2048 x 6144] = A[2048 x 4096] * Bt[6144 x 4096]^T + rank-2 LoRA.
// 8 waves (2M x 4N), wave-tile 64x96 as three 32-col strips (strip j in
// B-unit j). 3 phases/K-tile; 4 stage units (A,B0,B1,B2) of [128][64];
// steady-state waits vmcnt(10)/(12)/(10); dbuf by K-tile parity.
#define QSTAGE_A(KT) do {                                                    \
    const ushort* gp_ = A + (size_t)(m0 + w * 16 + srow) * Kz + (KT) * 64 + scol; \
    char* lp_ = qlds + ((KT) & 1) * 65536 + w * 2048;                        \
    gload16(gp_, lp_);  gload16(gp_ + 8 * Kz, lp_ + 1024);                   \
  } while (0)

#define QSTAGE_B(U, KT) do {                                                 \
    const ushort* gp_ = Bt + (size_t)(n0 + (U) * 128 + w * 16 + srow) * Kz   \
                          + (KT) * 64 + scol;                                \
    char* lp_ = qlds + ((KT) & 1) * 65536 + 16384 + (U) * 16384 + w * 2048;  \
    gload16(gp_, lp_);  gload16(gp_ + 8 * Kz, lp_ + 1024);                   \
  } while (0)

#define QLOAD_AF(BUF) do {                                                   \
    const char* ab_ = qlds + (BUF) * 65536 + (wr * 64 + lr) * 128;           \
    _Pragma("unroll") for (int fr = 0; fr < 4; fr++)                         \
    _Pragma("unroll") for (int ks = 0; ks < 2; ks++)                         \
      af[fr][ks] = *(const short8*)(ab_ + fr * 2048 + (((ks * 4 + g) * 16) ^ swz)); \
  } while (0)

#define QLOAD_BF(J, BUF) do {                                                \
    const char* bb_ = qlds + (BUF) * 65536 + 16384 + (J) * 16384 + (wc * 32 + lr) * 128; \
    _Pragma("unroll") for (int e = 0; e < 2; e++)                            \
    _Pragma("unroll") for (int ks = 0; ks < 2; ks++)                         \
      bf[e][ks] = *(const short8*)(bb_ + e * 2048 + (((ks * 4 + g) * 16) ^ swz)); \
  } while (0)

#define QMFMA(J) do {                                                        \
    __builtin_amdgcn_s_setprio(1);                                           \
    _Pragma("unroll") for (int fr = 0; fr < 4; fr++)                         \
    _Pragma("unroll") for (int e = 0; e < 2; e++)                            \
    _Pragma("unroll") for (int ks = 0; ks < 2; ks++)                         \
      acc[fr][(J) * 2 + e] = __builtin_amdgcn_mfma_f32_16x16x32_bf16(        \
          af[fr][ks], bf[e][ks], acc[fr][(J) * 2 + e], 0, 0, 0);             \
    __builtin_amdgcn_s_setprio(0);                                           \
  } while (0)

__global__ __launch_bounds__(512, 2) void k_gemmq(const ushort* __restrict__ A,
                                                  const ushort* __restrict__ Bt,
                                                  float* __restrict__ C,
                                                  const float* __restrict__ xa,
                                                  const float* __restrict__ qb,
                                                  const float* __restrict__ vb) {
  __shared__ char qlds[131072];
  // grid 16x16 = 256 blocks; bijective XCD swizzle
  const int flat = blockIdx.y * 16 + blockIdx.x;
  const int swz_id = (flat & 7) * 32 + (flat >> 3);
  const int m0 = (swz_id >> 4) * 128, n0 = (swz_id & 15) * 384;
  const int tid = threadIdx.x, lane = tid & 63, w = tid >> 6;
  const int wr = w >> 2, wc = w & 3;  // 2M x 4N
  const int lr = lane & 15, g = lane >> 4;
  const int swz = (lr & 7) * 16;
  const size_t Kz = 4096;
  const int NK = 64;
  const int srow = lane >> 3;
  const int scol = ((lane & 7) ^ (srow & 7)) * 8;

  floatx4 acc[4][6] = {};
  short8 af[4][2], bf[2][2];

  // prologue: tile0 complete + A,B0,B1 of tile1 (7 units, 14 gloads/wave)
  QSTAGE_A(0); QSTAGE_B(0, 0); QSTAGE_B(1, 0); QSTAGE_B(2, 0);
  QSTAGE_A(1); QSTAGE_B(0, 1); QSTAGE_B(1, 1);
  asm volatile("s_waitcnt vmcnt(10)" ::: "memory");  // A(0),B0(0) landed
  GBAR;

  for (int t = 0; t < NK; ++t) {
    const int c = t & 1;
    // P1: strip 0; stage B2(t+1) -> other buf
    QLOAD_AF(c); QLOAD_BF(0, c);
    if (t + 1 < NK) QSTAGE_B(2, t + 1);
    LGKM8;
    GBAR; LGKM0; QMFMA(0);
    if (t >= NK - 1) { VMCNT0; }  // guard B1(t) for P2
    else { asm volatile("s_waitcnt vmcnt(10)" ::: "memory"); }
    GBAR;
    // P2: strip 1; stage A(t+2), B0(t+2) -> this buf (slots last read at P1)
    QLOAD_BF(1, c);
    if (t + 2 < NK) { QSTAGE_A(t + 2); QSTAGE_B(0, t + 2); }
    GBAR; LGKM0; QMFMA(1);
    if (t >= NK - 2) { VMCNT0; }  // guard B2(t) for P3
    else { asm volatile("s_waitcnt vmcnt(12)" ::: "memory"); }
    GBAR;
    // P3: strip 2; stage B1(t+2) -> this buf (slot last read at P2)
    QLOAD_BF(2, c);
    if (t + 2 < NK) QSTAGE_B(1, t + 2);
    GBAR; LGKM0; QMFMA(2);
    if (t >= NK - 2) { VMCNT0; }  // guard A(t+1),B0(t+1) for next P1
    else { asm volatile("s_waitcnt vmcnt(10)" ::: "memory"); }
    GBAR;
  }

  // epilogue: C write + rank-2 LoRA (N = 6144)
#pragma unroll
  for (int fr = 0; fr < 4; fr++) {
    const int mb = m0 + wr * 64 + fr * 16 + g * 4;
    float4 xa4[4];
#pragma unroll
    for (int r = 0; r < 4; r++) xa4[r] = *(const float4*)&xa[(size_t)(mb + r) * 4];
#pragma unroll
    for (int j = 0; j < 3; j++)
#pragma unroll
      for (int e = 0; e < 2; e++) {
        const int n = n0 + j * 128 + wc * 32 + e * 16 + lr;
        const bool lq = (n < 4096), lv = (n >= 5120);
        float b0 = 0.f, b1 = 0.f;
        if (lq) { b0 = qb[n]; b1 = qb[4096 + n]; }
        else if (lv) { b0 = vb[n - 5120]; b1 = vb[1024 + n - 5120]; }
#pragma unroll
        for (int r = 0; r < 4; r++) {
          float cc = acc[fr][j * 2 + e][r];
          if (lq)      cc += xa4[r].x * b0 + xa4[r].y * b1;
          else if (lv) cc += xa4[r].z * b0 + xa4[r].w * b1;
          C[(size_t)(mb + r) * 6144 + n] = cc;
        }
      }
  }
}

// ==================== 256x256 8-phase/2-tile bf16 GEMM (out-proj) =========
#define STAGE_A(HALF, KT) do {                                               \
    const ushort* gp_ = A + (size_t)(m0 + (HALF) * 128 + w * 16 + srow) * Kz \
                          + kz0 + (KT) * 64 + scol;                          \
    char* lp_ = lds + ((KT) & 1) * 65536 + (HALF) * 16384 + w * 2048;        \
    gload16(gp_, lp_);                                                       \
    gload16(gp_ + 8 * Kz, lp_ + 1024);                                       \
  } while (0)

#define STAGE_B(HALF, KT) do {                                               \
    const ushort* gp_ = Bt + (size_t)(n0 + (HALF) * 128 + w * 16 + srow) * Kz\
                          + kz0 + (KT) * 64 + scol;                          \
    char* lp_ = lds + ((KT) & 1) * 65536 + 32768 + (HALF) * 16384 + w * 2048;\
    gload16(gp_, lp_);                                                       \
    gload16(gp_ + 8 * Kz, lp_ + 1024);                                       \
  } while (0)

#define LOAD_AF(QA, BUF) do {                                                \
    const char* ab_ = lds + (BUF) * 65536 + (QA) * 16384 + (wr * 64 + lr) * 128; \
    _Pragma("unroll") for (int fr = 0; fr < 4; fr++)                         \
    _Pragma("unroll") for (int ks = 0; ks < 2; ks++)                         \
      af[fr][ks] = *(const short8*)(ab_ + fr * 2048 + (((ks * 4 + g) * 16) ^ swz)); \
  } while (0)

#define LOAD_BF(QB, BUF, BF) do {                                            \
    const char* bb_ = lds + (BUF) * 65536 + 32768 + (QB) * 16384 + (wc * 32 + lr) * 128; \
    _Pragma("unroll") for (int fc = 0; fc < 2; fc++)                         \
    _Pragma("unroll") for (int ks = 0; ks < 2; ks++)                         \
      BF[fc][ks] = *(const short8*)(bb_ + fc * 2048 + (((ks * 4 + g) * 16) ^ swz)); \
  } while (0)

#define MFMA16(QA, QB, BF) do {                                              \
    __builtin_amdgcn_s_setprio(1);                                           \
    _Pragma("unroll") for (int fr = 0; fr < 4; fr++)                         \
    _Pragma("unroll") for (int fc = 0; fc < 2; fc++)                         \
    _Pragma("unroll") for (int ks = 0; ks < 2; ks++)                         \
      acc[(QA) * 4 + fr][(QB) * 2 + fc] = __builtin_amdgcn_mfma_f32_16x16x32_bf16( \
          af[fr][ks], BF[fc][ks], acc[(QA) * 4 + fr][(QB) * 2 + fc], 0, 0, 0);     \
    __builtin_amdgcn_s_setprio(0);                                           \
  } while (0)

#define VMCNT6 asm volatile("s_waitcnt vmcnt(6)" ::: "memory")

__global__ __launch_bounds__(512, 2) void k_gemm8(const ushort* __restrict__ A,
                                                  const ushort* __restrict__ Bt,
                                                  float* __restrict__ C0,
                                                  float* __restrict__ C1,
                                                  int N, int K) {
  __shared__ char lds[131072];
  const int nbx = gridDim.x;
  const int nwg = nbx * gridDim.y;
  const int flat = blockIdx.y * nbx + blockIdx.x;
  const int swz_id = (flat & 7) * (nwg >> 3) + (flat >> 3);
  const int m0 = (swz_id / nbx) * 256, n0 = (swz_id % nbx) * 256;
  const int kspan = K / gridDim.z;
  const int kz0 = blockIdx.z * kspan;
  const int NK = kspan >> 6;
  const int NJ = NK >> 1;
  float* __restrict__ Cout = blockIdx.z ? C1 : C0;

  const int tid = threadIdx.x, lane = tid & 63, w = tid >> 6;
  const int wr = w >> 2, wc = w & 3;
  const int lr = lane & 15, g = lane >> 4;
  const int swz = (lr & 7) * 16;
  const size_t Kz = (size_t)K;
  const int srow = lane >> 3;
  const int scol = ((lane & 7) ^ (srow & 7)) * 8;

  floatx4 acc[8][4] = {};
  short8 af[4][2], bf0[2][2], bf1[2][2];

  STAGE_A(0, 0); STAGE_B(0, 0); STAGE_A(1, 0); STAGE_B(1, 0);
  STAGE_A(0, 1); STAGE_B(0, 1); STAGE_A(1, 1);
  VMCNT6;
  GBAR;

  for (int j = 0; j < NJ; ++j) {
    const int t0 = 2 * j, t1 = 2 * j + 1;
    const bool last = (j == NJ - 1);
    LOAD_AF(0, 0);
    LOAD_BF(0, 0, bf0);
    STAGE_B(1, t1);
    GBAR; LGKM0; MFMA16(0, 0, bf0); GBAR;
    LOAD_BF(1, 0, bf1);
    if (t0 + 2 < NK) STAGE_A(0, t0 + 2);
    GBAR; LGKM0; MFMA16(0, 1, bf1); GBAR;
    LOAD_AF(1, 0);
    if (t0 + 2 < NK) STAGE_B(0, t0 + 2);
    GBAR; LGKM0; MFMA16(1, 1, bf1); GBAR;
    if (t0 + 2 < NK) STAGE_A(1, t0 + 2);
    if (last) { VMCNT0; } else { VMCNT6; }
    GBAR; LGKM0; MFMA16(1, 0, bf0); GBAR;
    LOAD_AF(0, 1);
    LOAD_BF(0, 1, bf0);
    if (t0 + 2 < NK) STAGE_B(1, t0 + 2);
    GBAR; LGKM0; MFMA16(0, 0, bf0); GBAR;
    LOAD_BF(1, 1, bf1);
    if (t1 + 2 < NK) STAGE_A(0, t1 + 2);
    GBAR; LGKM0; MFMA16(0, 1, bf1); GBAR;
    LOAD_AF(1, 1);
    if (t1 + 2 < NK) STAGE_B(0, t1 + 2);
    GBAR; LGKM0; MFMA16(1, 1, bf1); GBAR;
    if (t1 + 2 < NK) STAGE_A(1, t1 + 2);
    if (last) { VMCNT0; } else { VMCNT6; }
    GBAR; LGKM0; MFMA16(1, 0, bf0); GBAR;
  }

#pragma unroll
  for (int qa = 0; qa < 2; qa++)
#pragma unroll
    for (int fr = 0; fr < 4; fr++) {
      const int mb = m0 + qa * 128 + wr * 64 + fr * 16 + g * 4;
#pragma unroll
      for (int qb_ = 0; qb_ < 2; qb_++)
#pragma unroll
        for (int fc = 0; fc < 2; fc++) {
          const int n = n0 + qb_ * 128 + wc * 32 + fc * 16 + lr;
#pragma unroll
          for (int r = 0; r < 4; r++)
            Cout[(size_t)(mb + r) * N + n] = acc[qa * 4 + fr][qb_ * 2 + fc][r];
        }
    }
}

// ---- RoPE (interleaved pairs) + repack to (b,h,s,d) bf16 for Q and K ----
__global__ __launch_bounds__(256) void k_rope(const float* __restrict__ xqkv,
                                              const float* __restrict__ fcos,
                                              const float* __restrict__ fsin,
                                              ushort* __restrict__ Qb,
                                              ushort* __restrict__ Kb) {
  const int s = blockIdx.x, b = blockIdx.y;
  const float* row = xqkv + (size_t)(b * S_ + s) * 6144;
#pragma unroll
  for (int it = 0; it < 8; it++) {  // Q: 32 heads * 64 pairs
    int p2 = it * 256 + threadIdx.x;
    int h = p2 >> 6, p = p2 & 63;
    float2 ab = *(const float2*)(row + h * 128 + 2 * p);
    float c = fcos[s * 64 + p], sn = fsin[s * 64 + p];
    uint32_t pk = (uint32_t)f2bf(ab.x * c - ab.y * sn) |
                  ((uint32_t)f2bf(ab.x * sn + ab.y * c) << 16);
    *(uint32_t*)(Qb + ((size_t)(b * H_ + h) * S_ + s) * HD_ + 2 * p) = pk;
  }
#pragma unroll
  for (int it = 0; it < 2; it++) {  // K: 8 heads * 64 pairs
    int p2 = it * 256 + threadIdx.x;
    int h = p2 >> 6, p = p2 & 63;
    float2 ab = *(const float2*)(row + 4096 + h * 128 + 2 * p);
    float c = fcos[s * 64 + p], sn = fsin[s * 64 + p];
    uint32_t pk = (uint32_t)f2bf(ab.x * c - ab.y * sn) |
                  ((uint32_t)f2bf(ab.x * sn + ab.y * c) << 16);
    *(uint32_t*)(Kb + ((size_t)(b * KVH_ + h) * S_ + s) * HD_ + 2 * p) = pk;
  }
}

// ==================== flash attention, LDS-staged K/V ====================
#define FSTAGE(T, DB) do {                                                   \
    _Pragma("unroll") for (int i_ = 0; i_ < 4; i_++) {                       \
      gload16(Kg + (size_t)((T) * 64 + i_ * 16 + k_srow) * HD_ + k_scol,     \
              fls + (DB) * 16384 + i_ * 4096 + w * 1024);                    \
      gload16(Vg + (size_t)(i_ * 32 + v_srow) * S_ + (T) * 64 + v_scol,      \
              fls + 32768 + (DB) * 16384 + i_ * 4096 + w * 1024);            \
    }                                                                        \
  } while (0)

__global__ __launch_bounds__(256, 2) void k_flash(const ushort* __restrict__ Qb,
                                                  const ushort* __restrict__ Kb,
                                                  const ushort* __restrict__ Vt,
                                                  ushort* __restrict__ attn) {
  __shared__ char fls[73728];  // K dbuf 32KB | V dbuf 32KB | P 8KB
  const int qblk = (gridDim.x - 1) - blockIdx.x;  // heavy blocks first
  const int h = blockIdx.y, b = blockIdx.z;
  const int kvh = h >> 2;
  const int tid = threadIdx.x, w = tid >> 6, lane = tid & 63;
  const int lr = lane & 15, g = lane >> 4;
  const int swz = (lr & 7) * 16;
  const int qr0 = qblk * 64 + w * 16;
  const ushort* Qrow = Qb + ((size_t)(b * H_ + h) * S_ + qr0 + lr) * HD_;
  short8 qf[4];
#pragma unroll
  for (int ks = 0; ks < 4; ks++) qf[ks] = *(const short8*)(Qrow + ks * 32 + g * 8);
  const ushort* Kg = Kb + (size_t)(b * KVH_ + kvh) * S_ * HD_;
  const ushort* Vg = Vt + (size_t)(b * KVH_ + kvh) * HD_ * S_;
  char* Pw = fls + 65536 + w * 2048;
  const int q7 = lr & 7;
  const int k_srow = tid >> 4;
  const int k_scol = ((tid & 15) ^ (k_srow & 7)) * 8;
  const int v_srow = tid >> 3;
  const int v_scol = ((tid & 7) ^ (v_srow & 7)) * 8;

  float m_run = -1e30f, l_run = 0.f;
  floatx4 o[8] = {};
  const int nt = qblk + 1;

  FSTAGE(0, 0);
  asm volatile("s_waitcnt vmcnt(0)" ::: "memory");
  __builtin_amdgcn_s_barrier();

  for (int t = 0; t < nt; t++) {
    const int cur = t & 1;
    if (t + 1 < nt) FSTAGE(t + 1, cur ^ 1);
    const char* Kl = fls + cur * 16384;
    const char* Vl = fls + 32768 + cur * 16384;
    floatx4 s4[4] = {};
    __builtin_amdgcn_s_setprio(1);
#pragma unroll
    for (int mf = 0; mf < 4; mf++) {
      const char* Krow = Kl + (mf * 16 + lr) * 256;
#pragma unroll
      for (int ks = 0; ks < 4; ks++) {
        short8 kf = *(const short8*)(Krow + (((ks * 4 + g) * 16) ^ swz));
        s4[mf] = __builtin_amdgcn_mfma_f32_16x16x32_bf16(kf, qf[ks], s4[mf], 0, 0, 0);
      }
    }
    __builtin_amdgcn_s_setprio(0);
    const float scale = 0.088388347648318447f;  // 1/sqrt(128)
    float tm = -1e30f;
    if (t == nt - 1) {
#pragma unroll
      for (int mf = 0; mf < 4; mf++)
#pragma unroll
        for (int r = 0; r < 4; r++) {
          int kv = t * 64 + mf * 16 + g * 4 + r;
          float v = (kv > qr0 + lr) ? -1e30f : s4[mf][r] * scale;
          s4[mf][r] = v;
          tm = fmaxf(tm, v);
        }
    } else {
#pragma unroll
      for (int mf = 0; mf < 4; mf++)
#pragma unroll
        for (int r = 0; r < 4; r++) {
          float v = s4[mf][r] * scale;
          s4[mf][r] = v;
          tm = fmaxf(tm, v);
        }
    }
    tm = fmaxf(tm, __shfl_xor(tm, 16, 64));
    tm = fmaxf(tm, __shfl_xor(tm, 32, 64));
    float m_new = fmaxf(m_run, tm);
    float corr = __expf(m_run - m_new);
    float rs = 0.f;
#pragma unroll
    for (int mf = 0; mf < 4; mf++)
#pragma unroll
      for (int r = 0; r < 4; r++) {
        float p = __expf(s4[mf][r] - m_new);
        s4[mf][r] = p;
        rs += p;
      }
    rs += __shfl_xor(rs, 16, 64);
    rs += __shfl_xor(rs, 32, 64);
    l_run = l_run * corr + rs;
    m_run = m_new;
#pragma unroll
    for (int r = 0; r < 4; r++) {
      float cr = __shfl(corr, g * 4 + r, 64);
#pragma unroll
      for (int nf = 0; nf < 8; nf++) o[nf][r] *= cr;
    }
#pragma unroll
    for (int mf = 0; mf < 4; mf++) {
      uint2 pv;
      pv.x = (uint32_t)f2bf(s4[mf][0]) | ((uint32_t)f2bf(s4[mf][1]) << 16);
      pv.y = (uint32_t)f2bf(s4[mf][2]) | ((uint32_t)f2bf(s4[mf][3]) << 16);
      *(uint2*)(Pw + lr * 128 + ((mf * 32 + g * 8) ^ (q7 << 4))) = pv;
    }
    __builtin_amdgcn_s_setprio(1);
#pragma unroll
    for (int ks2 = 0; ks2 < 2; ks2++) {
      short8 pa = *(const short8*)(Pw + lr * 128 + ((ks2 * 64 + g * 16) ^ (q7 << 4)));
#pragma unroll
      for (int nf = 0; nf < 8; nf++) {
        short8 vf = *(const short8*)(Vl + (nf * 16 + lr) * 128 + (((ks2 * 4 + g) * 16) ^ swz));
        o[nf] = __builtin_amdgcn_mfma_f32_16x16x32_bf16(pa, vf, o[nf], 0, 0, 0);
      }
    }
    __builtin_amdgcn_s_setprio(0);
    asm volatile("s_waitcnt vmcnt(0)" ::: "memory");
    __builtin_amdgcn_s_barrier();
  }
  float linv = 1.0f / l_run;
  ushort* outp = attn + ((size_t)(b * S_) + qr0) * 4096 + h * 128;
#pragma unroll
  for (int r = 0; r < 4; r++) {
    float li = __shfl(linv, g * 4 + r, 64);
    ushort* orow = outp + (size_t)(g * 4 + r) * 4096;
#pragma unroll
    for (int nf = 0; nf < 8; nf++)
      orow[nf * 16 + lr] = f2bf(o[nf][r] * li);
  }
}

extern "C" void kernel_launch(void* const* d_in, const int* in_sizes, int n_in,
                              void* d_out, int out_size, void* d_ws, size_t ws_size,
                              hipStream_t stream) {
  (void)in_sizes; (void)n_in; (void)out_size; (void)ws_size;
  const float* x    = (const float*)d_in[0];
  const float* wq   = (const float*)d_in[1];
  const float* wk   = (const float*)d_in[2];
  const float* wv   = (const float*)d_in[3];
  const float* wo   = (const float*)d_in[4];
  const float* lqa  = (const float*)d_in[5];
  const float* lqb  = (const float*)d_in[6];
  const float* lva  = (const float*)d_in[7];
  const float* lvb  = (const float*)d_in[8];
  const float* fcos = (const float*)d_in[9];
  const float* fsin = (const float*)d_in[10];

  char* ws = (char*)d_ws;
  ushort* xb   = (ushort*)(ws + 0);           // x bf16              [0,16) MB
  ushort* wT   = (ushort*)(ws + 16777216);    // [wq|wk|wv]^T bf16   [16,64) MB (dead after QKV gemm)
  ushort* woT  = (ushort*)(ws + 67108864);    // wo^T bf16           [64,96) MB
  float*  xqkv = (float*) (ws + 100663296);   // 2048x6144 f32       [96,144) MB (dead after rope/V-tr)
  ushort* Qb   = (ushort*)(ws + 150994944);   // (b,h,s,d) bf16      [144,160) MB
  ushort* Kb   = (ushort*)(ws + 167772160);   // (b,kvh,s,d) bf16    [160,164) MB
  ushort* Vt   = (ushort*)(ws + 171966464);   // (b,kvh,d,s) bf16    [164,168) MB
  ushort* attn = (ushort*)(ws + 176160768);   // 2048x4096 bf16      [168,184) MB
  float*  xa   = (float*) (ws + 192937984);   // 2048x4 f32          [184,...)
  // split-K partials (32 MB each) in regions dead by out-proj time:
  float*  p0   = (float*) (ws + 16777216);    // reuses wT
  float*  p1   = (float*) (ws + 100663296);   // reuses xqkv

  // 1) fused x convert + LoRA projections; weight transposes
  k_cvtlora<<<2048, 256, 0, stream>>>(x, lqa, lva, xb, xa);
  k_tr4<<<dim3(64, 64), 256, 0, stream>>>(wq, wT, 4096, 4096);
  k_tr4<<<dim3(16, 64), 256, 0, stream>>>(wk, wT + (size_t)4096 * 4096, 1024, 4096);
  k_tr4<<<dim3(16, 64), 256, 0, stream>>>(wv, wT + (size_t)5120 * 4096, 1024, 4096);
  k_tr4<<<dim3(64, 64), 256, 0, stream>>>(wo, woT, 4096, 4096);
  // 2) fused QKV GEMM + LoRA epilogue -> xqkv f32 (grid 16x16 = 256 wg, full GPU)
  k_gemmq<<<dim3(16, 16), 512, 0, stream>>>(xb, wT, xqkv, xa, lqb, lvb);
  // 3) RoPE + repack Q,K ; V transpose (per batch)
  k_rope<<<dim3(1024, 2), 256, 0, stream>>>(xqkv, fcos, fsin, Qb, Kb);
  k_tr4<<<dim3(16, 16), 256, 0, stream>>>(xqkv + 5120, Vt, 6144, 1024);
  k_tr4<<<dim3(16, 16), 256, 0, stream>>>(xqkv + (size_t)1024 * 6144 + 5120, Vt + 1048576, 6144, 1024);
  // 4) flash attention -> attn bf16 (2048 x 4096)
  k_flash<<<dim3(16, 32, 2), 256, 0, stream>>>(Qb, Kb, Vt, attn);
  // 5) output projection, split-K x2 (256 wg, full GPU) -> partials -> d_out
  k_gemm8<<<dim3(16, 8, 2), 512, 0, stream>>>(attn, woT, p0, p1, 4096, 4096);
  k_add<<<8192, 256, 0, stream>>>(p0, p1, (float*)d_out, 2097152);
}

// Round 7
// 301.882 us; speedup vs baseline: 1.3228x; 1.1100x over previous
//
#include <hip/hip_runtime.h>
#include <stdint.h>

#define B_ 2
#define S_ 1024
#define D_ 4096
#define H_ 32
#define KVH_ 8
#define HD_ 128

typedef short short8 __attribute__((ext_vector_type(8)));
typedef float floatx4 __attribute__((ext_vector_type(4)));

__device__ __forceinline__ ushort f2bf(float f) {
  union { float f; uint32_t u; } v; v.f = f;
  return (ushort)((v.u + 0x7FFFu + ((v.u >> 16) & 1u)) >> 16);
}
__device__ __forceinline__ float bf2f(ushort u) {
  union { uint32_t x; float f; } v; v.x = ((uint32_t)u) << 16; return v.f;
}

__device__ __forceinline__ void gload16(const void* g, void* l) {
  __builtin_amdgcn_global_load_lds((__attribute__((address_space(1))) void*)g,
                                   (__attribute__((address_space(3))) void*)l,
                                   16, 0, 0);
}

// ---- fused: x f32 -> bf16  AND  xa = x @ [lora_q_a | lora_v_a] ----
__global__ __launch_bounds__(256) void k_cvtlora(const float* __restrict__ x,
                                                 const float* __restrict__ qa,
                                                 const float* __restrict__ va,
                                                 ushort* __restrict__ xb,
                                                 float* __restrict__ xa) {
  const int row = blockIdx.x, t = threadIdx.x;
  const float* xr = x + (size_t)row * D_;
  ushort* xo = xb + (size_t)row * D_;
  float a0 = 0, a1 = 0, a2 = 0, a3 = 0;
#pragma unroll
  for (int it = 0; it < 4; it++) {
    const int i = it * 1024 + t * 4;
    float4 v = *(const float4*)(xr + i);
    ushort o4[4] = {f2bf(v.x), f2bf(v.y), f2bf(v.z), f2bf(v.w)};
    *(uint2*)(xo + i) = *(uint2*)o4;
    float4 q0 = *(const float4*)(qa + 2 * i);
    float4 q1 = *(const float4*)(qa + 2 * i + 4);
    float4 w0 = *(const float4*)(va + 2 * i);
    float4 w1 = *(const float4*)(va + 2 * i + 4);
    a0 += v.x * q0.x + v.y * q0.z + v.z * q1.x + v.w * q1.z;
    a1 += v.x * q0.y + v.y * q0.w + v.z * q1.y + v.w * q1.w;
    a2 += v.x * w0.x + v.y * w0.z + v.z * w1.x + v.w * w1.z;
    a3 += v.x * w0.y + v.y * w0.w + v.z * w1.y + v.w * w1.w;
  }
#pragma unroll
  for (int off = 32; off; off >>= 1) {
    a0 += __shfl_down(a0, off, 64);
    a1 += __shfl_down(a1, off, 64);
    a2 += __shfl_down(a2, off, 64);
    a3 += __shfl_down(a3, off, 64);
  }
  __shared__ float red[4][4];
  const int w = t >> 6, lane = t & 63;
  if (lane == 0) { red[w][0] = a0; red[w][1] = a1; red[w][2] = a2; red[w][3] = a3; }
  __syncthreads();
  if (t < 4)
    xa[(size_t)row * 4 + t] = red[0][t] + red[1][t] + red[2][t] + red[3][t];
}

// ---- f32 [R x C] -> bf16 transposed [C x R]; 64x64 tiles; z picks src ----
__global__ __launch_bounds__(256) void k_trw2(const float* __restrict__ in0,
                                              const float* __restrict__ in1,
                                              ushort* __restrict__ out0,
                                              ushort* __restrict__ out1,
                                              int in_stride, int out_stride) {
  const float* in = blockIdx.z ? in1 : in0;
  ushort* out = blockIdx.z ? out1 : out0;
  __shared__ float t[64][65];
  const int n0 = blockIdx.x * 64, k0 = blockIdx.y * 64;
  const int c4 = (threadIdx.x & 15) * 4, r = threadIdx.x >> 4;
#pragma unroll
  for (int rr = 0; rr < 64; rr += 16) {
    float4 v = *(const float4*)&in[(size_t)(k0 + r + rr) * in_stride + n0 + c4];
    t[r + rr][c4] = v.x; t[r + rr][c4 + 1] = v.y;
    t[r + rr][c4 + 2] = v.z; t[r + rr][c4 + 3] = v.w;
  }
  __syncthreads();
#pragma unroll
  for (int rr = 0; rr < 64; rr += 16) {
    const int n = r + rr;
    ushort o4[4] = {f2bf(t[c4][n]), f2bf(t[c4 + 1][n]),
                    f2bf(t[c4 + 2][n]), f2bf(t[c4 + 3][n])};
    *(uint2*)&out[(size_t)(n0 + n) * out_stride + k0 + c4] = *(uint2*)o4;
  }
}

#define GBAR __builtin_amdgcn_s_barrier()
#define LGKM0 asm volatile("s_waitcnt lgkmcnt(0)" ::: "memory")
#define LGKM8 asm volatile("s_waitcnt lgkmcnt(8)" ::: "memory")
#define VMCNT0 asm volatile("s_waitcnt vmcnt(0)" ::: "memory")
#define VMCNT2 asm volatile("s_waitcnt vmcnt(2)" ::: "memory")
#define VMCNT6 asm volatile("s_waitcnt vmcnt(6)" ::: "memory")

// ==================== QKV GEMM: 128x384 tile, 256 blocks ====================
// C = A[2048x4096] * Bt[6144x4096]^T + rank-2 LoRA.  Output: bf16 xq for
// n<5120 (Q|K cols), and V cols (n>=5120) scattered TRANSPOSED into Vt.
#define QSTAGE_A(KT) do {                                                    \
    const ushort* gp_ = A + (size_t)(m0 + w * 16 + srow) * Kz + (KT) * 64 + scol; \
    char* lp_ = qlds + ((KT) & 1) * 65536 + w * 2048;                        \
    gload16(gp_, lp_);  gload16(gp_ + 8 * Kz, lp_ + 1024);                   \
  } while (0)

#define QSTAGE_B(U, KT) do {                                                 \
    const ushort* gp_ = Bt + (size_t)(n0 + (U) * 128 + w * 16 + srow) * Kz   \
                          + (KT) * 64 + scol;                                \
    char* lp_ = qlds + ((KT) & 1) * 65536 + 16384 + (U) * 16384 + w * 2048;  \
    gload16(gp_, lp_);  gload16(gp_ + 8 * Kz, lp_ + 1024);                   \
  } while (0)

#define QLOAD_AF(BUF) do {                                                   \
    const char* ab_ = qlds + (BUF) * 65536 + (wr * 64 + lr) * 128;           \
    _Pragma("unroll") for (int fr = 0; fr < 4; fr++)                         \
    _Pragma("unroll") for (int ks = 0; ks < 2; ks++)                         \
      af[fr][ks] = *(const short8*)(ab_ + fr * 2048 + (((ks * 4 + g) * 16) ^ swz)); \
  } while (0)

#define QLOAD_BF(J, BUF) do {                                                \
    const char* bb_ = qlds + (BUF) * 65536 + 16384 + (J) * 16384 + (wc * 32 + lr) * 128; \
    _Pragma("unroll") for (int e = 0; e < 2; e++)                            \
    _Pragma("unroll") for (int ks = 0; ks < 2; ks++)                         \
      bf[e][ks] = *(const short8*)(bb_ + e * 2048 + (((ks * 4 + g) * 16) ^ swz)); \
  } while (0)

#define QMFMA(J) do {                                                        \
    __builtin_amdgcn_s_setprio(1);                                           \
    _Pragma("unroll") for (int fr = 0; fr < 4; fr++)                         \
    _Pragma("unroll") for (int e = 0; e < 2; e++)                            \
    _Pragma("unroll") for (int ks = 0; ks < 2; ks++)                         \
      acc[fr][(J) * 2 + e] = __builtin_amdgcn_mfma_f32_16x16x32_bf16(        \
          af[fr][ks], bf[e][ks], acc[fr][(J) * 2 + e], 0, 0, 0);             \
    __builtin_amdgcn_s_setprio(0);                                           \
  } while (0)

__global__ __launch_bounds__(512, 2) void k_gemmq(const ushort* __restrict__ A,
                                                  const ushort* __restrict__ Bt,
                                                  ushort* __restrict__ xq,
                                                  ushort* __restrict__ Vt,
                                                  const float* __restrict__ xa,
                                                  const float* __restrict__ qb,
                                                  const float* __restrict__ vb) {
  __shared__ char qlds[131072];
  const int flat = blockIdx.y * 16 + blockIdx.x;
  const int swz_id = (flat & 7) * 32 + (flat >> 3);
  const int m0 = (swz_id >> 4) * 128, n0 = (swz_id & 15) * 384;
  const int tid = threadIdx.x, lane = tid & 63, w = tid >> 6;
  const int wr = w >> 2, wc = w & 3;
  const int lr = lane & 15, g = lane >> 4;
  const int swz = (lr & 7) * 16;
  const size_t Kz = 4096;
  const int NK = 64;
  const int srow = lane >> 3;
  const int scol = ((lane & 7) ^ (srow & 7)) * 8;

  floatx4 acc[4][6] = {};
  short8 af[4][2], bf[2][2];

  QSTAGE_A(0); QSTAGE_B(0, 0); QSTAGE_B(1, 0); QSTAGE_B(2, 0);
  QSTAGE_A(1); QSTAGE_B(0, 1); QSTAGE_B(1, 1);
  asm volatile("s_waitcnt vmcnt(10)" ::: "memory");
  GBAR;

  for (int t = 0; t < NK; ++t) {
    const int c = t & 1;
    QLOAD_AF(c); QLOAD_BF(0, c);
    if (t + 1 < NK) QSTAGE_B(2, t + 1);
    LGKM8;
    GBAR; LGKM0; QMFMA(0);
    if (t >= NK - 1) { VMCNT0; }
    else { asm volatile("s_waitcnt vmcnt(10)" ::: "memory"); }
    GBAR;
    QLOAD_BF(1, c);
    if (t + 2 < NK) { QSTAGE_A(t + 2); QSTAGE_B(0, t + 2); }
    GBAR; LGKM0; QMFMA(1);
    if (t >= NK - 2) { VMCNT0; }
    else { asm volatile("s_waitcnt vmcnt(12)" ::: "memory"); }
    GBAR;
    QLOAD_BF(2, c);
    if (t + 2 < NK) QSTAGE_B(1, t + 2);
    GBAR; LGKM0; QMFMA(2);
    if (t >= NK - 2) { VMCNT0; }
    else { asm volatile("s_waitcnt vmcnt(10)" ::: "memory"); }
    GBAR;
  }

  // epilogue: bf16 xq for n<5120 (+Q LoRA); V cols transposed into Vt (+V LoRA)
#pragma unroll
  for (int fr = 0; fr < 4; fr++) {
    const int mb = m0 + wr * 64 + fr * 16 + g * 4;
    const int bb = mb >> 10, s0 = mb & 1023;
    float4 xa4[4];
#pragma unroll
    for (int r = 0; r < 4; r++) xa4[r] = *(const float4*)&xa[(size_t)(mb + r) * 4];
#pragma unroll
    for (int j = 0; j < 3; j++)
#pragma unroll
      for (int e = 0; e < 2; e++) {
        const int n = n0 + j * 128 + wc * 32 + e * 16 + lr;
        if (n < 5120) {
          const bool lq = (n < 4096);
          float b0 = 0.f, b1 = 0.f;
          if (lq) { b0 = qb[n]; b1 = qb[4096 + n]; }
#pragma unroll
          for (int r = 0; r < 4; r++) {
            float cc = acc[fr][j * 2 + e][r];
            if (lq) cc += xa4[r].x * b0 + xa4[r].y * b1;
            xq[(size_t)(mb + r) * 6144 + n] = f2bf(cc);
          }
        } else {
          const int vcol = n - 5120;
          const float b0 = vb[vcol], b1 = vb[1024 + vcol];
          ushort v4[4];
#pragma unroll
          for (int r = 0; r < 4; r++)
            v4[r] = f2bf(acc[fr][j * 2 + e][r] + xa4[r].z * b0 + xa4[r].w * b1);
          *(uint2*)&Vt[(size_t)((bb * 8 + (vcol >> 7)) * 128 + (vcol & 127)) * 1024 + s0] =
              *(uint2*)v4;
        }
      }
  }
}

// ==================== out-proj GEMM: 128x256 tile, 256 blocks ==============
// d_out[2048x4096] = attn[2048x4096] * woT[4096x4096]^T, f32 out.
// 2 phases/K-tile; units A,B0,B1; steady vmcnt(6) per phase end.
#define OSTAGE_A(KT) do {                                                    \
    const ushort* gp_ = A + (size_t)(m0 + w * 16 + srow) * Kz + (KT) * 64 + scol; \
    char* lp_ = olds + ((KT) & 1) * 49152 + w * 2048;                        \
    gload16(gp_, lp_);  gload16(gp_ + 8 * Kz, lp_ + 1024);                   \
  } while (0)

#define OSTAGE_B(U, KT) do {                                                 \
    const ushort* gp_ = Bt + (size_t)(n0 + (U) * 128 + w * 16 + srow) * Kz   \
                          + (KT) * 64 + scol;                                \
    char* lp_ = olds + ((KT) & 1) * 49152 + 16384 + (U) * 16384 + w * 2048;  \
    gload16(gp_, lp_);  gload16(gp_ + 8 * Kz, lp_ + 1024);                   \
  } while (0)

#define OLOAD_AF(BUF) do {                                                   \
    const char* ab_ = olds + (BUF) * 49152 + (wr * 64 + lr) * 128;           \
    _Pragma("unroll") for (int fr = 0; fr < 4; fr++)                         \
    _Pragma("unroll") for (int ks = 0; ks < 2; ks++)                         \
      af[fr][ks] = *(const short8*)(ab_ + fr * 2048 + (((ks * 4 + g) * 16) ^ swz)); \
  } while (0)

#define OLOAD_BF(U, BUF) do {                                                \
    const char* bb_ = olds + (BUF) * 49152 + 16384 + (U) * 16384 + (wc * 32 + lr) * 128; \
    _Pragma("unroll") for (int e = 0; e < 2; e++)                            \
    _Pragma("unroll") for (int ks = 0; ks < 2; ks++)                         \
      bf[e][ks] = *(const short8*)(bb_ + e * 2048 + (((ks * 4 + g) * 16) ^ swz)); \
  } while (0)

#define OMFMA(U) do {                                                        \
    __builtin_amdgcn_s_setprio(1);                                           \
    _Pragma("unroll") for (int fr = 0; fr < 4; fr++)                         \
    _Pragma("unroll") for (int e = 0; e < 2; e++)                            \
    _Pragma("unroll") for (int ks = 0; ks < 2; ks++)                         \
      acc[fr][(U) * 2 + e] = __builtin_amdgcn_mfma_f32_16x16x32_bf16(        \
          af[fr][ks], bf[e][ks], acc[fr][(U) * 2 + e], 0, 0, 0);             \
    __builtin_amdgcn_s_setprio(0);                                           \
  } while (0)

__global__ __launch_bounds__(512, 2) void k_gemmo(const ushort* __restrict__ A,
                                                  const ushort* __restrict__ Bt,
                                                  float* __restrict__ C) {
  __shared__ char olds[98304];
  const int flat = blockIdx.y * 16 + blockIdx.x;
  const int swz_id = (flat & 7) * 32 + (flat >> 3);
  const int m0 = (swz_id >> 4) * 128, n0 = (swz_id & 15) * 256;
  const int tid = threadIdx.x, lane = tid & 63, w = tid >> 6;
  const int wr = w >> 2, wc = w & 3;
  const int lr = lane & 15, g = lane >> 4;
  const int swz = (lr & 7) * 16;
  const size_t Kz = 4096;
  const int NK = 64;
  const int srow = lane >> 3;
  const int scol = ((lane & 7) ^ (srow & 7)) * 8;

  floatx4 acc[4][4] = {};
  short8 af[4][2], bf[2][2];

  // prologue: tile0 (A,B0,B1) + tile1 (A,B0) = 10 gloads/wave
  OSTAGE_A(0); OSTAGE_B(0, 0); OSTAGE_B(1, 0);
  OSTAGE_A(1); OSTAGE_B(0, 1);
  asm volatile("s_waitcnt vmcnt(4)" ::: "memory");
  GBAR;

  for (int t = 0; t < NK; ++t) {
    const int c = t & 1;
    // P1: A x B0; stage B1(t+1) -> other buf
    OLOAD_AF(c); OLOAD_BF(0, c);
    if (t + 1 < NK) OSTAGE_B(1, t + 1);
    LGKM8;
    GBAR; LGKM0; OMFMA(0);
    if (t == NK - 1) { VMCNT0; } else { VMCNT6; }  // retire B1(t)
    GBAR;
    // P2: A x B1; stage A(t+2),B0(t+2) -> this buf (last read at P1)
    OLOAD_BF(1, c);
    if (t + 2 < NK) { OSTAGE_A(t + 2); OSTAGE_B(0, t + 2); }
    GBAR; LGKM0; OMFMA(1);
    if (t < NK - 2) { VMCNT6; }        // retire A(t+1),B0(t+1)
    else if (t == NK - 2) { VMCNT2; }
    GBAR;
  }

#pragma unroll
  for (int fr = 0; fr < 4; fr++) {
    const int mb = m0 + wr * 64 + fr * 16 + g * 4;
#pragma unroll
    for (int j = 0; j < 2; j++)
#pragma unroll
      for (int e = 0; e < 2; e++) {
        const int n = n0 + j * 128 + wc * 32 + e * 16 + lr;
#pragma unroll
        for (int r = 0; r < 4; r++)
          C[(size_t)(mb + r) * 4096 + n] = acc[fr][j * 2 + e][r];
      }
  }
}

// ---- RoPE (interleaved pairs) from bf16 xq -> (b,h,s,d) bf16 Q and K ----
__global__ __launch_bounds__(256) void k_rope(const ushort* __restrict__ xq,
                                              const float* __restrict__ fcos,
                                              const float* __restrict__ fsin,
                                              ushort* __restrict__ Qb,
                                              ushort* __restrict__ Kb) {
  const int s = blockIdx.x, b = blockIdx.y;
  const ushort* row = xq + (size_t)(b * S_ + s) * 6144;
#pragma unroll
  for (int it = 0; it < 8; it++) {  // Q: 32 heads * 64 pairs
    int p2 = it * 256 + threadIdx.x;
    int h = p2 >> 6, p = p2 & 63;
    uint32_t u = *(const uint32_t*)(row + h * 128 + 2 * p);
    float a = bf2f((ushort)u), bb = bf2f((ushort)(u >> 16));
    float c = fcos[s * 64 + p], sn = fsin[s * 64 + p];
    uint32_t pk = (uint32_t)f2bf(a * c - bb * sn) |
                  ((uint32_t)f2bf(a * sn + bb * c) << 16);
    *(uint32_t*)(Qb + ((size_t)(b * H_ + h) * S_ + s) * HD_ + 2 * p) = pk;
  }
#pragma unroll
  for (int it = 0; it < 2; it++) {  // K: 8 heads * 64 pairs
    int p2 = it * 256 + threadIdx.x;
    int h = p2 >> 6, p = p2 & 63;
    uint32_t u = *(const uint32_t*)(row + 4096 + h * 128 + 2 * p);
    float a = bf2f((ushort)u), bb = bf2f((ushort)(u >> 16));
    float c = fcos[s * 64 + p], sn = fsin[s * 64 + p];
    uint32_t pk = (uint32_t)f2bf(a * c - bb * sn) |
                  ((uint32_t)f2bf(a * sn + bb * c) << 16);
    *(uint32_t*)(Kb + ((size_t)(b * KVH_ + h) * S_ + s) * HD_ + 2 * p) = pk;
  }
}

// ==================== flash attention, 128 q-rows/block ====================
// grid (8, 32, 2); 4 waves, each owns two 16-row q-groups (a: +0, b: +64).
// K tile 64x128 + V tile 128x64 double-buffered in LDS; shared across groups.
#define FSTAGE(T, DB) do {                                                   \
    _Pragma("unroll") for (int i_ = 0; i_ < 4; i_++) {                       \
      gload16(Kg + (size_t)((T) * 64 + i_ * 16 + k_srow) * HD_ + k_scol,     \
              fls + (DB) * 16384 + i_ * 4096 + w * 1024);                    \
      gload16(Vg + (size_t)(i_ * 32 + v_srow) * S_ + (T) * 64 + v_scol,      \
              fls + 32768 + (DB) * 16384 + i_ * 4096 + w * 1024);            \
    }                                                                        \
  } while (0)

__global__ __launch_bounds__(256, 2) void k_flash(const ushort* __restrict__ Qb,
                                                  const ushort* __restrict__ Kb,
                                                  const ushort* __restrict__ Vt,
                                                  ushort* __restrict__ attn) {
  __shared__ char fls[81920];  // K dbuf 32KB | V dbuf 32KB | P 16KB
  const int qblk = (gridDim.x - 1) - blockIdx.x;  // 0..7, heavy first
  const int h = blockIdx.y, b = blockIdx.z;
  const int kvh = h >> 2;
  const int tid = threadIdx.x, w = tid >> 6, lane = tid & 63;
  const int lr = lane & 15, g = lane >> 4;
  const int swz = (lr & 7) * 16;
  const int qra = qblk * 128 + w * 16;     // group a rows; group b = +64
  const ushort* Qrow = Qb + ((size_t)(b * H_ + h) * S_ + qra + lr) * HD_;
  short8 qfa[4], qfb[4];
#pragma unroll
  for (int ks = 0; ks < 4; ks++) {
    qfa[ks] = *(const short8*)(Qrow + ks * 32 + g * 8);
    qfb[ks] = *(const short8*)(Qrow + 64 * HD_ + ks * 32 + g * 8);
  }
  const ushort* Kg = Kb + (size_t)(b * KVH_ + kvh) * S_ * HD_;
  const ushort* Vg = Vt + (size_t)(b * KVH_ + kvh) * HD_ * S_;
  char* Pw = fls + 65536 + w * 4096;       // a at +0, b at +2048
  const int q7 = lr & 7;
  const int k_srow = tid >> 4;
  const int k_scol = ((tid & 15) ^ (k_srow & 7)) * 8;
  const int v_srow = tid >> 3;
  const int v_scol = ((tid & 7) ^ (v_srow & 7)) * 8;
  const float scale = 0.088388347648318447f;  // 1/sqrt(128)

  float m_a = -1e30f, l_a = 0.f, m_b = -1e30f, l_b = 0.f;
  floatx4 oa[8] = {}, ob[8] = {};
  const int nt = 2 * qblk + 2;
  const int lastA = 2 * qblk;  // last (and mask) tile for group a

  FSTAGE(0, 0);
  VMCNT0;
  GBAR;

  for (int t = 0; t < nt; t++) {
    const int cur = t & 1;
    if (t + 1 < nt) FSTAGE(t + 1, cur ^ 1);
    const char* Kl = fls + cur * 16384;
    const char* Vl = fls + 32768 + cur * 16384;
    // ---------------- group a ----------------
    if (t <= lastA) {
      floatx4 s4[4] = {};
      __builtin_amdgcn_s_setprio(1);
#pragma unroll
      for (int mf = 0; mf < 4; mf++) {
        const char* Krow = Kl + (mf * 16 + lr) * 256;
#pragma unroll
        for (int ks = 0; ks < 4; ks++) {
          short8 kf = *(const short8*)(Krow + (((ks * 4 + g) * 16) ^ swz));
          s4[mf] = __builtin_amdgcn_mfma_f32_16x16x32_bf16(kf, qfa[ks], s4[mf], 0, 0, 0);
        }
      }
      __builtin_amdgcn_s_setprio(0);
      float tm = -1e30f;
      if (t == lastA) {
#pragma unroll
        for (int mf = 0; mf < 4; mf++)
#pragma unroll
          for (int r = 0; r < 4; r++) {
            int kv = t * 64 + mf * 16 + g * 4 + r;
            float v = (kv > qra + lr) ? -1e30f : s4[mf][r] * scale;
            s4[mf][r] = v; tm = fmaxf(tm, v);
          }
      } else {
#pragma unroll
        for (int mf = 0; mf < 4; mf++)
#pragma unroll
          for (int r = 0; r < 4; r++) {
            float v = s4[mf][r] * scale;
            s4[mf][r] = v; tm = fmaxf(tm, v);
          }
      }
      tm = fmaxf(tm, __shfl_xor(tm, 16, 64));
      tm = fmaxf(tm, __shfl_xor(tm, 32, 64));
      float m_new = fmaxf(m_a, tm);
      float corr = __expf(m_a - m_new);
      float rs = 0.f;
#pragma unroll
      for (int mf = 0; mf < 4; mf++)
#pragma unroll
        for (int r = 0; r < 4; r++) {
          float p = __expf(s4[mf][r] - m_new);
          s4[mf][r] = p; rs += p;
        }
      rs += __shfl_xor(rs, 16, 64);
      rs += __shfl_xor(rs, 32, 64);
      l_a = l_a * corr + rs; m_a = m_new;
#pragma unroll
      for (int r = 0; r < 4; r++) {
        float cr = __shfl(corr, g * 4 + r, 64);
#pragma unroll
        for (int nf = 0; nf < 8; nf++) oa[nf][r] *= cr;
      }
#pragma unroll
      for (int mf = 0; mf < 4; mf++) {
        uint2 pv;
        pv.x = (uint32_t)f2bf(s4[mf][0]) | ((uint32_t)f2bf(s4[mf][1]) << 16);
        pv.y = (uint32_t)f2bf(s4[mf][2]) | ((uint32_t)f2bf(s4[mf][3]) << 16);
        *(uint2*)(Pw + lr * 128 + ((mf * 32 + g * 8) ^ (q7 << 4))) = pv;
      }
    }
    // ---------------- group b ----------------
    {
      floatx4 s4[4] = {};
      __builtin_amdgcn_s_setprio(1);
#pragma unroll
      for (int mf = 0; mf < 4; mf++) {
        const char* Krow = Kl + (mf * 16 + lr) * 256;
#pragma unroll
        for (int ks = 0; ks < 4; ks++) {
          short8 kf = *(const short8*)(Krow + (((ks * 4 + g) * 16) ^ swz));
          s4[mf] = __builtin_amdgcn_mfma_f32_16x16x32_bf16(kf, qfb[ks], s4[mf], 0, 0, 0);
        }
      }
      __builtin_amdgcn_s_setprio(0);
      float tm = -1e30f;
      if (t == nt - 1) {
#pragma unroll
        for (int mf = 0; mf < 4; mf++)
#pragma unroll
          for (int r = 0; r < 4; r++) {
            int kv = t * 64 + mf * 16 + g * 4 + r;
            float v = (kv > qra + 64 + lr) ? -1e30f : s4[mf][r] * scale;
            s4[mf][r] = v; tm = fmaxf(tm, v);
          }
      } else {
#pragma unroll
        for (int mf = 0; mf < 4; mf++)
#pragma unroll
          for (int r = 0; r < 4; r++) {
            float v = s4[mf][r] * scale;
            s4[mf][r] = v; tm = fmaxf(tm, v);
          }
      }
      tm = fmaxf(tm, __shfl_xor(tm, 16, 64));
      tm = fmaxf(tm, __shfl_xor(tm, 32, 64));
      float m_new = fmaxf(m_b, tm);
      float corr = __expf(m_b - m_new);
      float rs = 0.f;
#pragma unroll
      for (int mf = 0; mf < 4; mf++)
#pragma unroll
        for (int r = 0; r < 4; r++) {
          float p = __expf(s4[mf][r] - m_new);
          s4[mf][r] = p; rs += p;
        }
      rs += __shfl_xor(rs, 16, 64);
      rs += __shfl_xor(rs, 32, 64);
      l_b = l_b * corr + rs; m_b = m_new;
#pragma unroll
      for (int r = 0; r < 4; r++) {
        float cr = __shfl(corr, g * 4 + r, 64);
#pragma unroll
        for (int nf = 0; nf < 8; nf++) ob[nf][r] *= cr;
      }
#pragma unroll
      for (int mf = 0; mf < 4; mf++) {
        uint2 pv;
        pv.x = (uint32_t)f2bf(s4[mf][0]) | ((uint32_t)f2bf(s4[mf][1]) << 16);
        pv.y = (uint32_t)f2bf(s4[mf][2]) | ((uint32_t)f2bf(s4[mf][3]) << 16);
        *(uint2*)(Pw + 2048 + lr * 128 + ((mf * 32 + g * 8) ^ (q7 << 4))) = pv;
      }
    }
    // ---------------- PV (V fragments shared by both groups) -------------
    __builtin_amdgcn_s_setprio(1);
#pragma unroll
    for (int ks2 = 0; ks2 < 2; ks2++) {
      short8 pb = *(const short8*)(Pw + 2048 + lr * 128 + ((ks2 * 64 + g * 16) ^ (q7 << 4)));
      short8 pa = pb;
      if (t <= lastA)
        pa = *(const short8*)(Pw + lr * 128 + ((ks2 * 64 + g * 16) ^ (q7 << 4)));
#pragma unroll
      for (int nf = 0; nf < 8; nf++) {
        short8 vf = *(const short8*)(Vl + (nf * 16 + lr) * 128 + (((ks2 * 4 + g) * 16) ^ swz));
        if (t <= lastA)
          oa[nf] = __builtin_amdgcn_mfma_f32_16x16x32_bf16(pa, vf, oa[nf], 0, 0, 0);
        ob[nf] = __builtin_amdgcn_mfma_f32_16x16x32_bf16(pb, vf, ob[nf], 0, 0, 0);
      }
    }
    __builtin_amdgcn_s_setprio(0);
    VMCNT0;
    GBAR;
  }
  const float linva = 1.0f / l_a, linvb = 1.0f / l_b;
  ushort* outp = attn + ((size_t)(b * S_) + qra) * 4096 + h * 128;
#pragma unroll
  for (int r = 0; r < 4; r++) {
    float lia = __shfl(linva, g * 4 + r, 64);
    float lib = __shfl(linvb, g * 4 + r, 64);
    ushort* orow = outp + (size_t)(g * 4 + r) * 4096;
#pragma unroll
    for (int nf = 0; nf < 8; nf++) {
      orow[nf * 16 + lr] = f2bf(oa[nf][r] * lia);
      orow[(size_t)64 * 4096 + nf * 16 + lr] = f2bf(ob[nf][r] * lib);
    }
  }
}

extern "C" void kernel_launch(void* const* d_in, const int* in_sizes, int n_in,
                              void* d_out, int out_size, void* d_ws, size_t ws_size,
                              hipStream_t stream) {
  (void)in_sizes; (void)n_in; (void)out_size; (void)ws_size;
  const float* x    = (const float*)d_in[0];
  const float* wq   = (const float*)d_in[1];
  const float* wk   = (const float*)d_in[2];
  const float* wv   = (const float*)d_in[3];
  const float* wo   = (const float*)d_in[4];
  const float* lqa  = (const float*)d_in[5];
  const float* lqb  = (const float*)d_in[6];
  const float* lva  = (const float*)d_in[7];
  const float* lvb  = (const float*)d_in[8];
  const float* fcos = (const float*)d_in[9];
  const float* fsin = (const float*)d_in[10];

  char* ws = (char*)d_ws;
  ushort* xb   = (ushort*)(ws + 0);           // x bf16              [0,16) MB
  ushort* wT   = (ushort*)(ws + 16777216);    // [wq|wk|wv]^T bf16   [16,64) MB
  ushort* woT  = (ushort*)(ws + 67108864);    // wo^T bf16           [64,96) MB
  ushort* xq   = (ushort*)(ws + 100663296);   // 2048x6144 bf16      [96,121) MB
  ushort* Qb   = (ushort*)(ws + 150994944);   // (b,h,s,d) bf16      [144,160) MB
  ushort* Kb   = (ushort*)(ws + 167772160);   // (b,kvh,s,d) bf16    [160,164) MB
  ushort* Vt   = (ushort*)(ws + 171966464);   // (b,kvh,d,s) bf16    [164,168) MB
  ushort* attn = (ushort*)(ws + 176160768);   // 2048x4096 bf16      [168,184) MB
  float*  xa   = (float*) (ws + 192937984);   // 2048x4 f32

  // 1) fused x convert + LoRA; weight transposes (wq/wo merged, wk/wv merged)
  k_cvtlora<<<2048, 256, 0, stream>>>(x, lqa, lva, xb, xa);
  k_trw2<<<dim3(64, 64, 2), 256, 0, stream>>>(wq, wo, wT, woT, 4096, 4096);
  k_trw2<<<dim3(16, 64, 2), 256, 0, stream>>>(wk, wv, wT + (size_t)4096 * 4096,
                                              wT + (size_t)5120 * 4096, 1024, 4096);
  // 2) fused QKV GEMM + LoRA -> bf16 xq (Q|K) + transposed Vt (V)
  k_gemmq<<<dim3(16, 16), 512, 0, stream>>>(xb, wT, xq, Vt, xa, lqb, lvb);
  // 3) RoPE + repack Q,K
  k_rope<<<dim3(1024, 2), 256, 0, stream>>>(xq, fcos, fsin, Qb, Kb);
  // 4) flash attention -> attn bf16
  k_flash<<<dim3(8, 32, 2), 256, 0, stream>>>(Qb, Kb, Vt, attn);
  // 5) output projection -> d_out f32 (grid 16x16 = 256 wg, full GPU)
  k_gemmo<<<dim3(16, 16), 512, 0, stream>>>(attn, woT, (float*)d_out);
}